// Round 16
// baseline (466.239 us; speedup 1.0000x reference)
//
#include <hip/hip_runtime.h>
#include <hip/hip_cooperative_groups.h>
#include <math.h>
#include <stdint.h>

namespace cg = cooperative_groups;

// ---------------------------------------------------------------------------
// KAN forward, split-bf16 MFMA version, round 19: single cooperative launch.
//   R18 proven: whole-network fusion works (362.6 us, best; fused_net 306.7
//   ~= sum of parts). Residual accounting: ~22 us fixed overhead PER LAUNCH
//   (2 launches -> ~45 us). This round removes the last boundary: setup is
//   fused as phase 0 with a grid-wide barrier (hipLaunchCooperativeKernel +
//   this_grid().sync() — the blessed mechanism for cross-block deps; W is
//   read by all blocks). Geometry already co-resident: 256 blocks x 512 thr
//   x 128 KB LDS = 1 block/CU x 256 CUs exactly.
//   Setup redistribution: block b preps col b of all 3 layers (same
//   coalesced pattern) + encodes h0 slice [b*4096,(b+1)*4096). Bit-identical
//   math. All network phases byte-identical to R18.
//   - GEMM phase: R10 config (512 thr / 8 waves / 128 rows, split-K parity,
//     32x32x16 chain-broken MFMA, LDS dbuf, 1 barrier/pair), 120.4 us/layer.
//   - layer3 phase: closed-form uniform cubic basis, quad-per-row reduce.
//   Augmented-K GEMM per layer: K = 9F (8 spline bases + 1 silu per feature).
//   W prefolded, split into bf16 hi/lo pair, staged via global_load_lds.
//   3-product split emulation: Ah*Wh + Al*Wh + Ah*Wl  (error ~2^-16 rel).
// ---------------------------------------------------------------------------

#define N_PTS 32768

using short8 = __attribute__((ext_vector_type(8))) short;
using f32x4  = __attribute__((ext_vector_type(4))) float;
using f32x16 = __attribute__((ext_vector_type(16))) float;

union Frag { short8 v; uint32_t u[4]; };

__device__ __forceinline__ uint32_t bf16rne(float f) {
    uint32_t u = __float_as_uint(f);
    return (u + 0x7FFFu + ((u >> 16) & 1u)) >> 16;
}
__device__ __forceinline__ float bf16tof(uint32_t h) { return __uint_as_float(h << 16); }

// pack bf16-trunc(x0) into lo16, bf16-trunc(x1) into hi16 — one v_perm_b32
__device__ __forceinline__ uint32_t pkhi(uint32_t x0, uint32_t x1) {
    return __builtin_amdgcn_perm(x1, x0, 0x07060302u);
}

// async global->LDS, 16B per lane (wave-uniform base + lane*16 semantics)
__device__ __forceinline__ void gld16(const void* g, void* lds) {
    __builtin_amdgcn_global_load_lds(
        (const __attribute__((address_space(1))) void*)(uintptr_t)g,
        (__attribute__((address_space(3))) void*)(uint32_t)(uintptr_t)lds,
        16, 0, 0);
}

// ---------------------------------------------------------------------------
// fast uniform cubic B-spline, trunc-split bf16 fragments.
// t = (x+2.2)/0.4 ; i = floor(t) ; slot j nonzero for j = i-3..i with value
// q_{i-j}.  Pair p (slots 2p,2p+1) selected from 5 packed candidates by i-2p.
__device__ __forceinline__ void build_basis_frag(float x, Frag& ah, Frag& al) {
    float t  = (x + 2.2f) * 2.5f;
    float fl = floorf(t);
    int   i  = (int)fl;
    float w  = t - fl;
    float w2 = w * w, w3 = w2 * w;
    const float s = 1.0f / 6.0f;
    float q0 = w3 * s;                                     // d == 0 (j == i)
    float q1 = (-3.f * w3 + 3.f * w2 + 3.f * w + 1.f) * s; // d == 1
    float q2 = (3.f * w3 - 6.f * w2 + 4.f) * s;            // d == 2
    float omw = 1.f - w;
    float q3 = omw * omw * omw * s;                        // d == 3
    uint32_t u0 = __float_as_uint(q0), u1 = __float_as_uint(q1);
    uint32_t u2 = __float_as_uint(q2), u3 = __float_as_uint(q3);
    // exact residual of the truncated head, then bf16-trunc via perm
    uint32_t r0 = __float_as_uint(q0 - __uint_as_float(u0 & 0xFFFF0000u));
    uint32_t r1 = __float_as_uint(q1 - __uint_as_float(u1 & 0xFFFF0000u));
    uint32_t r2 = __float_as_uint(q2 - __uint_as_float(u2 & 0xFFFF0000u));
    uint32_t r3 = __float_as_uint(q3 - __uint_as_float(u3 & 0xFFFF0000u));
    uint32_t PH0 = pkhi(u0, 0u), PH1 = pkhi(u1, u0), PH2 = pkhi(u2, u1),
             PH3 = pkhi(u3, u2), PH4 = pkhi(0u, u3);
    uint32_t PL0 = pkhi(r0, 0u), PL1 = pkhi(r1, r0), PL2 = pkhi(r2, r1),
             PL3 = pkhi(r3, r2), PL4 = pkhi(0u, r3);
#pragma unroll
    for (int p = 0; p < 4; ++p) {
        bool c0 = (i == 2 * p), c1 = (i == 2 * p + 1), c2 = (i == 2 * p + 2),
             c3 = (i == 2 * p + 3), c4 = (i == 2 * p + 4);
        ah.u[p] = c0 ? PH0 : c1 ? PH1 : c2 ? PH2 : c3 ? PH3 : c4 ? PH4 : 0u;
        al.u[p] = c0 ? PL0 : c1 ? PL1 : c2 ? PL2 : c3 ? PL3 : c4 ? PL4 : 0u;
    }
}

__device__ __forceinline__ void build_silu_frag(const float* __restrict__ xp, Frag& ah, Frag& al) {
    float4 a = *(const float4*)xp;
    float4 b = *(const float4*)(xp + 4);
    float xs[8] = {a.x, a.y, a.z, a.w, b.x, b.y, b.z, b.w};
#pragma unroll
    for (int p = 0; p < 4; ++p) {
        float x0 = xs[p * 2], x1 = xs[p * 2 + 1];
        float v0 = x0 / (1.f + __expf(-x0));
        float v1 = x1 / (1.f + __expf(-x1));
        uint32_t w0 = __float_as_uint(v0), w1 = __float_as_uint(v1);
        uint32_t l0 = __float_as_uint(v0 - __uint_as_float(w0 & 0xFFFF0000u));
        uint32_t l1 = __float_as_uint(v1 - __uint_as_float(w1 & 0xFFFF0000u));
        ah.u[p] = pkhi(w0, w1);
        al.u[p] = pkhi(l0, l1);
    }
}

// ---------------------------------------------------------------------------
// Prep one output column (col) of one layer: fold sw*ss and bw into
// split-bf16 Wh/Wl, layout [(k>>3)][col][k&7] (16B-contiguous per k-group).
__device__ __forceinline__ void prep_col(
    const float* __restrict__ bw, const float* __restrict__ sw,
    const float* __restrict__ ss, short* __restrict__ Wh,
    short* __restrict__ Wl, int F, int col, int tid, int nthr) {
    const int KG = (9 * F) / 8;       // 36 or 288 k-groups
    for (int kg = tid; kg < KG; kg += nthr) {
        float wv[8];
        if (kg < F) {                  // spline block: k = kg*8 + j
            const float* sp = sw + ((size_t)col * F + kg) * 8;
            float4 a = *(const float4*)sp;
            float4 b = *(const float4*)(sp + 4);
            float sv = ss[(size_t)col * F + kg];
            wv[0] = a.x * sv; wv[1] = a.y * sv; wv[2] = a.z * sv; wv[3] = a.w * sv;
            wv[4] = b.x * sv; wv[5] = b.y * sv; wv[6] = b.z * sv; wv[7] = b.w * sv;
        } else {                       // base block: k = 8F + f, f = (kg-F)*8 + j
            const float* bp = bw + (size_t)col * F + (kg - F) * 8;
            float4 a = *(const float4*)bp;
            float4 b = *(const float4*)(bp + 4);
            wv[0] = a.x; wv[1] = a.y; wv[2] = a.z; wv[3] = a.w;
            wv[4] = b.x; wv[5] = b.y; wv[6] = b.z; wv[7] = b.w;
        }
        uint32_t ph[4], pl[4];
#pragma unroll
        for (int q = 0; q < 4; ++q) {
            uint32_t h0b = bf16rne(wv[2 * q]);
            uint32_t h1b = bf16rne(wv[2 * q + 1]);
            uint32_t l0b = bf16rne(wv[2 * q]     - bf16tof(h0b));
            uint32_t l1b = bf16rne(wv[2 * q + 1] - bf16tof(h1b));
            ph[q] = (h0b & 0xFFFFu) | (h1b << 16);
            pl[q] = (l0b & 0xFFFFu) | (l1b << 16);
        }
        const size_t ob = ((size_t)kg * 256 + col) * 8;   // shorts; *2 = 16B aligned
        uint4 vh = {ph[0], ph[1], ph[2], ph[3]};
        uint4 vl = {pl[0], pl[1], pl[2], pl[3]};
        *(uint4*)(Wh + ob) = vh;
        *(uint4*)(Wl + ob) = vl;
    }
}

// ---------------------------------------------------------------------------
// One GEMM layer phase: out(128 rows,256) = Aug(h)(128,9F) @ W(9F,256),
// split-bf16 32x32x16 MFMA, split-K parity, chain-broken groups (R10 code).
// Wave (rg, ks): 32 rows, chunks c with c%2==ks. Caller must __syncthreads()
// before the next phase touches WB.
// A-frag layout (32x32x16): row = lane&31, k = (lane>>5)*8 + j.
// B-frag layout:            col = lane&31, k = (lane>>5)*8 + j.
// C/D layout:               col = lane&31, row = (reg&3)+8*(reg>>2)+4*(lane>>5).
template <int F>
__device__ __forceinline__ void layer_phase(
    const int tid, const int row0,
    const float* __restrict__ hin,
    const short* __restrict__ Wh, const short* __restrict__ Wl,
    float* __restrict__ out,
    short (&WB)[2][2][2][8192]) {
    constexpr int KBC = F / 4;         // basis chunks (8F/32)
    constexpr int KSC = F / 32;        // silu chunks
    constexpr int NC  = KBC + KSC;
    constexpr int NP  = (NC + 1) / 2;  // chunk pairs (last may be singleton)

    const int wv   = tid >> 6;
    const int rg   = wv & 3;           // row-group 0..3
    const int ks   = wv >> 2;          // chunk parity 0..1
    const int lane = tid & 63;
    const int lc   = lane & 31;        // A row / B col within tile
    const int half = lane >> 5;        // k-subgroup
    const int r    = row0 + rg * 32 + lc;   // this lane's A row
    const float* hrow = hin + (size_t)r * F;

    f32x16 acc[8];
#pragma unroll
    for (int a = 0; a < 8; ++a)
#pragma unroll
        for (int e = 0; e < 16; ++e) acc[a][e] = 0.f;

    auto stage_pair = [&](int p, int buf) {
#pragma unroll
        for (int cip = 0; cip < 2; ++cip) {
            int c = 2 * p + cip;
            if (c < NC) {
                const size_t gof = (size_t)c * 8192;
#pragma unroll
                for (int i = 0; i < 2; ++i) {
                    int e = tid * 8 + i * 4096;
                    gld16(Wh + gof + e, &WB[buf][cip][0][e]);
                    gld16(Wl + gof + e, &WB[buf][cip][1][e]);
                }
            }
        }
    };

    // stage pair 0 into buf 0
    stage_pair(0, 0);

    // preload x for my first chunk (c0 = ks, always a basis chunk):
    // feature = c*4 + kh*2 + half
    float xreg[2];
#pragma unroll
    for (int kh = 0; kh < 2; ++kh)
        xreg[kh] = hrow[ks * 4 + kh * 2 + half];
    __syncthreads();

    for (int p = 0; p < NP; ++p) {
        const int cur = p & 1;
        if (p + 1 < NP) stage_pair(p + 1, cur ^ 1);

        const int c = 2 * p + ks;      // my chunk this pair
        if (c < NC) {
            // ---- A fragments (registers), one per k-half ----
            Frag ah[2], al[2];
            if (c < KBC) {
                float x0 = xreg[0], x1 = xreg[1];
                if (c + 2 < KBC) {   // prefetch activations for my next chunk
#pragma unroll
                    for (int kh = 0; kh < 2; ++kh)
                        xreg[kh] = hrow[(c + 2) * 4 + kh * 2 + half];
                }
                build_basis_frag(x0, ah[0], al[0]);
                build_basis_frag(x1, ah[1], al[1]);
            } else {
                const int fb = (c - KBC) * 32 + half * 8;
#pragma unroll
                for (int kh = 0; kh < 2; ++kh)
                    build_silu_frag(&hrow[fb + kh * 16], ah[kh], al[kh]);
            }

            // ---- MFMA: product-major ct-groups of 4 (chain-broken) ----
            const short* WHp = WB[cur][ks][0];
            const short* WLp = WB[cur][ks][1];
#pragma unroll
            for (int kh = 0; kh < 2; ++kh) {
#pragma unroll
                for (int g = 0; g < 2; ++g) {
                    const int cb  = g * 4;
                    const int ob  = ((kh * 2 + half) * 256 + cb * 32 + lc) * 8;
                    Frag w0, w1, w2, w3;
                    w0.v = *(const short8*)&WHp[ob];
                    w1.v = *(const short8*)&WHp[ob + 256];
                    w2.v = *(const short8*)&WHp[ob + 512];
                    w3.v = *(const short8*)&WHp[ob + 768];
                    acc[cb + 0] = __builtin_amdgcn_mfma_f32_32x32x16_bf16(ah[kh].v, w0.v, acc[cb + 0], 0, 0, 0);
                    acc[cb + 1] = __builtin_amdgcn_mfma_f32_32x32x16_bf16(ah[kh].v, w1.v, acc[cb + 1], 0, 0, 0);
                    acc[cb + 2] = __builtin_amdgcn_mfma_f32_32x32x16_bf16(ah[kh].v, w2.v, acc[cb + 2], 0, 0, 0);
                    acc[cb + 3] = __builtin_amdgcn_mfma_f32_32x32x16_bf16(ah[kh].v, w3.v, acc[cb + 3], 0, 0, 0);
                    acc[cb + 0] = __builtin_amdgcn_mfma_f32_32x32x16_bf16(al[kh].v, w0.v, acc[cb + 0], 0, 0, 0);
                    acc[cb + 1] = __builtin_amdgcn_mfma_f32_32x32x16_bf16(al[kh].v, w1.v, acc[cb + 1], 0, 0, 0);
                    acc[cb + 2] = __builtin_amdgcn_mfma_f32_32x32x16_bf16(al[kh].v, w2.v, acc[cb + 2], 0, 0, 0);
                    acc[cb + 3] = __builtin_amdgcn_mfma_f32_32x32x16_bf16(al[kh].v, w3.v, acc[cb + 3], 0, 0, 0);
                    Frag v0, v1, v2, v3;
                    v0.v = *(const short8*)&WLp[ob];
                    v1.v = *(const short8*)&WLp[ob + 256];
                    v2.v = *(const short8*)&WLp[ob + 512];
                    v3.v = *(const short8*)&WLp[ob + 768];
                    acc[cb + 0] = __builtin_amdgcn_mfma_f32_32x32x16_bf16(ah[kh].v, v0.v, acc[cb + 0], 0, 0, 0);
                    acc[cb + 1] = __builtin_amdgcn_mfma_f32_32x32x16_bf16(ah[kh].v, v1.v, acc[cb + 1], 0, 0, 0);
                    acc[cb + 2] = __builtin_amdgcn_mfma_f32_32x32x16_bf16(ah[kh].v, v2.v, acc[cb + 2], 0, 0, 0);
                    acc[cb + 3] = __builtin_amdgcn_mfma_f32_32x32x16_bf16(ah[kh].v, v3.v, acc[cb + 3], 0, 0, 0);
                }
            }
        }
        __syncthreads();
    }

    // ---- cross-ks reduction via LDS (WB reused as 32K-float scratch) ----
    // Tile (rg, ks, cti) = 1024 floats at ((rg*2+ks)*4+cti)*1024; within:
    // e4*256 + lane*4 (contiguous 16B/lane — conflict-free b128 pattern).
    // Wave (rg, ks) writes its partials for the OTHER half's col-tiles, then
    // reads partner's partials for its OWN half, adds, stores to global.
    float* red = (float*)WB;
    {
        float* wp = red + (size_t)((rg * 2 + ks) * 4) * 1024 + lane * 4;
        if (ks == 0) {
#pragma unroll
            for (int cti = 0; cti < 4; ++cti)
#pragma unroll
                for (int e4 = 0; e4 < 4; ++e4) {
                    f32x4 v = {acc[4 + cti][e4 * 4 + 0], acc[4 + cti][e4 * 4 + 1],
                               acc[4 + cti][e4 * 4 + 2], acc[4 + cti][e4 * 4 + 3]};
                    *(f32x4*)(wp + cti * 1024 + e4 * 256) = v;
                }
        } else {
#pragma unroll
            for (int cti = 0; cti < 4; ++cti)
#pragma unroll
                for (int e4 = 0; e4 < 4; ++e4) {
                    f32x4 v = {acc[cti][e4 * 4 + 0], acc[cti][e4 * 4 + 1],
                               acc[cti][e4 * 4 + 2], acc[cti][e4 * 4 + 3]};
                    *(f32x4*)(wp + cti * 1024 + e4 * 256) = v;
                }
        }
    }
    __syncthreads();
    {
        const float* rp = red + (size_t)((rg * 2 + (1 - ks)) * 4) * 1024 + lane * 4;
        if (ks == 0) {
#pragma unroll
            for (int cti = 0; cti < 4; ++cti) {
                const int colg = cti * 32 + lc;
#pragma unroll
                for (int e4 = 0; e4 < 4; ++e4) {
                    f32x4 v = *(const f32x4*)(rp + cti * 1024 + e4 * 256);
#pragma unroll
                    for (int j = 0; j < 4; ++j) {
                        const int rgi  = e4 * 4 + j;
                        const int rowg = row0 + rg * 32 + (rgi & 3) + 8 * (rgi >> 2) + 4 * half;
                        out[(size_t)rowg * 256 + colg] = acc[cti][rgi] + v[j];
                    }
                }
            }
        } else {
#pragma unroll
            for (int cti = 0; cti < 4; ++cti) {
                const int colg = (4 + cti) * 32 + lc;
#pragma unroll
                for (int e4 = 0; e4 < 4; ++e4) {
                    f32x4 v = *(const f32x4*)(rp + cti * 1024 + e4 * 256);
#pragma unroll
                    for (int j = 0; j < 4; ++j) {
                        const int rgi  = e4 * 4 + j;
                        const int rowg = row0 + rg * 32 + (rgi & 3) + 8 * (rgi >> 2) + 4 * half;
                        out[(size_t)rowg * 256 + colg] = acc[4 + cti][rgi] + v[j];
                    }
                }
            }
        }
    }
}

// ---------------------------------------------------------------------------
// Mega-kernel: setup phase (block b = col b of all layers + h0 slice) ->
// grid sync -> 3 GEMM phases -> final layer. One launch for everything.
__global__ __launch_bounds__(512, 2)
void mega_kernel(const float* __restrict__ x,   const float* __restrict__ freq,
                 const float* __restrict__ bw0, const float* __restrict__ sw0,
                 const float* __restrict__ ss0,
                 const float* __restrict__ bw1, const float* __restrict__ sw1,
                 const float* __restrict__ ss1,
                 const float* __restrict__ bw2, const float* __restrict__ sw2,
                 const float* __restrict__ ss2,
                 short* __restrict__ Wh0, short* __restrict__ Wl0,
                 short* __restrict__ Wh1, short* __restrict__ Wl1,
                 short* __restrict__ Wh2, short* __restrict__ Wl2,
                 float* __restrict__ h0, float* __restrict__ hA,
                 float* __restrict__ hB,
                 const float* __restrict__ sw3, const float* __restrict__ ss3,
                 const float* __restrict__ bw3, float* __restrict__ outp) {
    __shared__ short WB[2][2][2][8192];   // 128 KB, reused by every phase
    const int bid = blockIdx.x;
    const int tid = threadIdx.x;
    const int row0 = bid * 128;

    // ---- phase 0: setup (prep col=bid for 3 layers + encode h0 slice) ----
    prep_col(bw0, sw0, ss0, Wh0, Wl0, 32,  bid, tid, 512);
    prep_col(bw1, sw1, ss1, Wh1, Wl1, 256, bid, tid, 512);
    prep_col(bw2, sw2, ss2, Wh2, Wl2, 256, bid, tid, 512);
#pragma unroll
    for (int i = 0; i < 8; ++i) {
        const int idx = bid * 4096 + i * 512 + tid;   // < N_PTS*32
        const int n = idx >> 5, l = idx & 31;
        const float xv = x[n];
        h0[idx] = (l < 16) ? sinf(xv * freq[l]) : cosf(xv * freq[l - 16]);
    }

    __threadfence();
    cg::this_grid().sync();   // W + h0 visible to all blocks

    // ---- network phases (byte-identical to R18) ----
    layer_phase<32>(tid, row0, h0, Wh0, Wl0, hA, WB);
    __syncthreads();
    layer_phase<256>(tid, row0, hA, Wh1, Wl1, hB, WB);
    __syncthreads();
    layer_phase<256>(tid, row0, hB, Wh2, Wl2, hA, WB);
    __syncthreads();

    // ---- final layer (n_out=1): quad-per-row, closed-form cubic basis ----
    const int lr  = tid >> 2;          // local row 0..127
    const int qq  = tid & 3;           // quad lane -> feature block
    const int row = row0 + lr;
    const float* hrow = hA + (size_t)row * 256;
    const int fb = qq * 64;
    float acc = 0.f;
#pragma unroll 4
    for (int it = 0; it < 16; ++it) {
        float4 xv = *(const float4*)(hrow + fb + it * 4);
        float xs[4] = {xv.x, xv.y, xv.z, xv.w};
#pragma unroll
        for (int j = 0; j < 4; ++j) {
            const int f = fb + it * 4 + j;
            const float x2 = xs[j];
            float t  = (x2 + 2.2f) * 2.5f;
            float fl = floorf(t);
            int   i  = (int)fl;
            float w  = t - fl;
            float w2 = w * w, w3 = w2 * w;
            const float s = 1.0f / 6.0f;
            float q0 = w3 * s;
            float q1 = (-3.f * w3 + 3.f * w2 + 3.f * w + 1.f) * s;
            float q2 = (3.f * w3 - 6.f * w2 + 4.f) * s;
            float omw = 1.f - w;
            float q3 = omw * omw * omw * s;
            const float* swf = sw3 + f * 8;
            int j0 = i, j1 = i - 1, j2 = i - 2, j3 = i - 3;
            float v0 = swf[j0 < 0 ? 0 : (j0 > 7 ? 7 : j0)];
            float v1 = swf[j1 < 0 ? 0 : (j1 > 7 ? 7 : j1)];
            float v2 = swf[j2 < 0 ? 0 : (j2 > 7 ? 7 : j2)];
            float v3 = swf[j3 < 0 ? 0 : (j3 > 7 ? 7 : j3)];
            float dot = 0.0f;
            dot += (j0 >= 0 && j0 < 8) ? q0 * v0 : 0.f;
            dot += (j1 >= 0 && j1 < 8) ? q1 * v1 : 0.f;
            dot += (j2 >= 0 && j2 < 8) ? q2 * v2 : 0.f;
            dot += (j3 >= 0 && j3 < 8) ? q3 * v3 : 0.f;
            acc = fmaf(dot, ss3[f], acc);
            acc = fmaf(x2 / (1.0f + __expf(-x2)), bw3[f], acc);
        }
    }
    acc += __shfl_xor(acc, 1);
    acc += __shfl_xor(acc, 2);
    if (qq == 0) outp[row] = acc;
}

// ---------------------------------------------------------------------------
// ws layout (bytes)
#define WH0_OFF 0u
#define WL0_OFF (WH0_OFF + 147456u)      // 288*256*2
#define WH1_OFF (WL0_OFF + 147456u)
#define WL1_OFF (WH1_OFF + 1179648u)     // 2304*256*2
#define WH2_OFF (WL1_OFF + 1179648u)
#define WL2_OFF (WH2_OFF + 1179648u)
#define H0_OFF  (WL2_OFF + 1179648u)     // 32768*32*4
#define HA_OFF  (H0_OFF + 4194304u)      // 32768*256*4
#define HB_OFF  (HA_OFF + 33554432u)
// total = 76,316,672 B

extern "C" void kernel_launch(void* const* d_in, const int* in_sizes, int n_in,
                              void* d_out, int out_size, void* d_ws, size_t ws_size,
                              hipStream_t stream) {
    const float* x    = (const float*)d_in[0];
    const float* freq = (const float*)d_in[1];
    const float* bw0  = (const float*)d_in[2];
    const float* sw0  = (const float*)d_in[3];
    const float* ss0  = (const float*)d_in[4];
    const float* bw1  = (const float*)d_in[5];
    const float* sw1  = (const float*)d_in[6];
    const float* ss1  = (const float*)d_in[7];
    const float* bw2  = (const float*)d_in[8];
    const float* sw2  = (const float*)d_in[9];
    const float* ss2  = (const float*)d_in[10];
    const float* bw3  = (const float*)d_in[11];
    const float* sw3  = (const float*)d_in[12];
    const float* ss3  = (const float*)d_in[13];

    char* ws = (char*)d_ws;
    short* Wh0 = (short*)(ws + WH0_OFF);
    short* Wl0 = (short*)(ws + WL0_OFF);
    short* Wh1 = (short*)(ws + WH1_OFF);
    short* Wl1 = (short*)(ws + WL1_OFF);
    short* Wh2 = (short*)(ws + WH2_OFF);
    short* Wl2 = (short*)(ws + WL2_OFF);
    float* h0 = (float*)(ws + H0_OFF);
    float* hA = (float*)(ws + HA_OFF);
    float* hB = (float*)(ws + HB_OFF);
    float* outp = (float*)d_out;

    void* args[] = {
        (void*)&x,   (void*)&freq,
        (void*)&bw0, (void*)&sw0, (void*)&ss0,
        (void*)&bw1, (void*)&sw1, (void*)&ss1,
        (void*)&bw2, (void*)&sw2, (void*)&ss2,
        (void*)&Wh0, (void*)&Wl0, (void*)&Wh1, (void*)&Wl1,
        (void*)&Wh2, (void*)&Wl2,
        (void*)&h0,  (void*)&hA,  (void*)&hB,
        (void*)&sw3, (void*)&ss3, (void*)&bw3, (void*)&outp};

    hipLaunchCooperativeKernel((const void*)mega_kernel,
                               dim3(N_PTS / 128), dim3(512),
                               args, 0, stream);
}

// Round 17
// 360.585 us; speedup vs baseline: 1.2930x; 1.2930x over previous
//
#include <hip/hip_runtime.h>
#include <math.h>
#include <stdint.h>

// ---------------------------------------------------------------------------
// KAN forward, split-bf16 MFMA version, round 20: restore R18 (best: 362.6).
//   R19's cooperative single-launch REGRESSED (380-466 us: grid.sync is an
//   atomic spin across 256 blocks + cooperative dispatch overhead lands
//   inside the kernel). Two launches with HW dependency handling win.
//   Structure (all measured-best):
//   - setup_kernel: 3 preps (coalesced k-group reads, packed 16B writes) +
//     encode (thread-per-element, coalesced).
//   - fused_net: whole network in one launch. Network is pointwise per-row
//     (block b owns rows [128b,128b+128) in every layer) -> phases separated
//     by per-block __syncthreads only.
//     * GEMM phase: R10 config (512 thr / 8 waves / 128 rows, split-K parity,
//       32x32x16 chain-broken MFMA, LDS dbuf, 1 barrier/pair). 120.4 us/layer
//       standalone; 8 schedule probes (R7-R14) all null/negative — floor at
//       2 waves/SIMD (acc[8] f32x16 = 128 VGPR/wave).
//     * layer3 phase: closed-form uniform cubic basis, quad-per-row reduce.
//   Fusion of layer3 INTO the GEMM epilogue ruled out by measurement (R15
//   +50us gathers / R16 2.5GB spill). Cooperative launch ruled out (R19).
//   Augmented-K GEMM per layer: K = 9F (8 spline bases + 1 silu per feature).
//   W prefolded, split into bf16 hi/lo pair, staged via global_load_lds.
//   3-product split emulation: Ah*Wh + Al*Wh + Ah*Wl  (error ~2^-16 rel).
// ---------------------------------------------------------------------------

#define N_PTS 32768

using short8 = __attribute__((ext_vector_type(8))) short;
using f32x4  = __attribute__((ext_vector_type(4))) float;
using f32x16 = __attribute__((ext_vector_type(16))) float;

union Frag { short8 v; uint32_t u[4]; };

__device__ __forceinline__ uint32_t bf16rne(float f) {
    uint32_t u = __float_as_uint(f);
    return (u + 0x7FFFu + ((u >> 16) & 1u)) >> 16;
}
__device__ __forceinline__ float bf16tof(uint32_t h) { return __uint_as_float(h << 16); }

// pack bf16-trunc(x0) into lo16, bf16-trunc(x1) into hi16 — one v_perm_b32
__device__ __forceinline__ uint32_t pkhi(uint32_t x0, uint32_t x1) {
    return __builtin_amdgcn_perm(x1, x0, 0x07060302u);
}

// async global->LDS, 16B per lane (wave-uniform base + lane*16 semantics)
__device__ __forceinline__ void gld16(const void* g, void* lds) {
    __builtin_amdgcn_global_load_lds(
        (const __attribute__((address_space(1))) void*)(uintptr_t)g,
        (__attribute__((address_space(3))) void*)(uint32_t)(uintptr_t)lds,
        16, 0, 0);
}

// ---------------------------------------------------------------------------
// fast uniform cubic B-spline, trunc-split bf16 fragments.
// t = (x+2.2)/0.4 ; i = floor(t) ; slot j nonzero for j = i-3..i with value
// q_{i-j}.  Pair p (slots 2p,2p+1) selected from 5 packed candidates by i-2p.
__device__ __forceinline__ void build_basis_frag(float x, Frag& ah, Frag& al) {
    float t  = (x + 2.2f) * 2.5f;
    float fl = floorf(t);
    int   i  = (int)fl;
    float w  = t - fl;
    float w2 = w * w, w3 = w2 * w;
    const float s = 1.0f / 6.0f;
    float q0 = w3 * s;                                     // d == 0 (j == i)
    float q1 = (-3.f * w3 + 3.f * w2 + 3.f * w + 1.f) * s; // d == 1
    float q2 = (3.f * w3 - 6.f * w2 + 4.f) * s;            // d == 2
    float omw = 1.f - w;
    float q3 = omw * omw * omw * s;                        // d == 3
    uint32_t u0 = __float_as_uint(q0), u1 = __float_as_uint(q1);
    uint32_t u2 = __float_as_uint(q2), u3 = __float_as_uint(q3);
    // exact residual of the truncated head, then bf16-trunc via perm
    uint32_t r0 = __float_as_uint(q0 - __uint_as_float(u0 & 0xFFFF0000u));
    uint32_t r1 = __float_as_uint(q1 - __uint_as_float(u1 & 0xFFFF0000u));
    uint32_t r2 = __float_as_uint(q2 - __uint_as_float(u2 & 0xFFFF0000u));
    uint32_t r3 = __float_as_uint(q3 - __uint_as_float(u3 & 0xFFFF0000u));
    uint32_t PH0 = pkhi(u0, 0u), PH1 = pkhi(u1, u0), PH2 = pkhi(u2, u1),
             PH3 = pkhi(u3, u2), PH4 = pkhi(0u, u3);
    uint32_t PL0 = pkhi(r0, 0u), PL1 = pkhi(r1, r0), PL2 = pkhi(r2, r1),
             PL3 = pkhi(r3, r2), PL4 = pkhi(0u, r3);
#pragma unroll
    for (int p = 0; p < 4; ++p) {
        bool c0 = (i == 2 * p), c1 = (i == 2 * p + 1), c2 = (i == 2 * p + 2),
             c3 = (i == 2 * p + 3), c4 = (i == 2 * p + 4);
        ah.u[p] = c0 ? PH0 : c1 ? PH1 : c2 ? PH2 : c3 ? PH3 : c4 ? PH4 : 0u;
        al.u[p] = c0 ? PL0 : c1 ? PL1 : c2 ? PL2 : c3 ? PL3 : c4 ? PL4 : 0u;
    }
}

__device__ __forceinline__ void build_silu_frag(const float* __restrict__ xp, Frag& ah, Frag& al) {
    float4 a = *(const float4*)xp;
    float4 b = *(const float4*)(xp + 4);
    float xs[8] = {a.x, a.y, a.z, a.w, b.x, b.y, b.z, b.w};
#pragma unroll
    for (int p = 0; p < 4; ++p) {
        float x0 = xs[p * 2], x1 = xs[p * 2 + 1];
        float v0 = x0 / (1.f + __expf(-x0));
        float v1 = x1 / (1.f + __expf(-x1));
        uint32_t w0 = __float_as_uint(v0), w1 = __float_as_uint(v1);
        uint32_t l0 = __float_as_uint(v0 - __uint_as_float(w0 & 0xFFFF0000u));
        uint32_t l1 = __float_as_uint(v1 - __uint_as_float(w1 & 0xFFFF0000u));
        ah.u[p] = pkhi(w0, w1);
        al.u[p] = pkhi(l0, l1);
    }
}

// ---------------------------------------------------------------------------
// Fused setup: blocks [0,256) prep L0, [256,512) prep L1, [512,768) prep L2,
// [768, 768+4096) encode. Prep: one block per output col; thread = k-group
// (8 k's): 32B coalesced sw/bw reads. Encode: thread-per-element, coalesced.
__global__ __launch_bounds__(256)
void setup_kernel(const float* __restrict__ x,    const float* __restrict__ freq,
                  const float* __restrict__ bw0,  const float* __restrict__ sw0,
                  const float* __restrict__ ss0,
                  const float* __restrict__ bw1,  const float* __restrict__ sw1,
                  const float* __restrict__ ss1,
                  const float* __restrict__ bw2,  const float* __restrict__ sw2,
                  const float* __restrict__ ss2,
                  short* __restrict__ Wh0, short* __restrict__ Wl0,
                  short* __restrict__ Wh1, short* __restrict__ Wl1,
                  short* __restrict__ Wh2, short* __restrict__ Wl2,
                  float* __restrict__ h0) {
    const int bid = blockIdx.x;
    const int tid = threadIdx.x;
    if (bid < 768) {
        const float *bw, *sw, *ss;
        short *Wh, *Wl;
        int F, col;
        if (bid < 256)      { bw = bw0; sw = sw0; ss = ss0; Wh = Wh0; Wl = Wl0; F = 32;  col = bid; }
        else if (bid < 512) { bw = bw1; sw = sw1; ss = ss1; Wh = Wh1; Wl = Wl1; F = 256; col = bid - 256; }
        else                { bw = bw2; sw = sw2; ss = ss2; Wh = Wh2; Wl = Wl2; F = 256; col = bid - 512; }
        const int KG = (9 * F) / 8;       // 36 or 288 k-groups
        for (int kg = tid; kg < KG; kg += 256) {
            float wv[8];
            if (kg < F) {                  // spline block: k = kg*8 + j
                const float* sp = sw + ((size_t)col * F + kg) * 8;
                float4 a = *(const float4*)sp;
                float4 b = *(const float4*)(sp + 4);
                float sv = ss[(size_t)col * F + kg];
                wv[0] = a.x * sv; wv[1] = a.y * sv; wv[2] = a.z * sv; wv[3] = a.w * sv;
                wv[4] = b.x * sv; wv[5] = b.y * sv; wv[6] = b.z * sv; wv[7] = b.w * sv;
            } else {                       // base block: k = 8F + f, f = (kg-F)*8 + j
                const float* bp = bw + (size_t)col * F + (kg - F) * 8;
                float4 a = *(const float4*)bp;
                float4 b = *(const float4*)(bp + 4);
                wv[0] = a.x; wv[1] = a.y; wv[2] = a.z; wv[3] = a.w;
                wv[4] = b.x; wv[5] = b.y; wv[6] = b.z; wv[7] = b.w;
            }
            uint32_t ph[4], pl[4];
#pragma unroll
            for (int q = 0; q < 4; ++q) {
                uint32_t h0b = bf16rne(wv[2 * q]);
                uint32_t h1b = bf16rne(wv[2 * q + 1]);
                uint32_t l0b = bf16rne(wv[2 * q]     - bf16tof(h0b));
                uint32_t l1b = bf16rne(wv[2 * q + 1] - bf16tof(h1b));
                ph[q] = (h0b & 0xFFFFu) | (h1b << 16);
                pl[q] = (l0b & 0xFFFFu) | (l1b << 16);
            }
            const size_t ob = ((size_t)kg * 256 + col) * 8;   // shorts; *2 = 16B aligned
            uint4 vh = {ph[0], ph[1], ph[2], ph[3]};
            uint4 vl = {pl[0], pl[1], pl[2], pl[3]};
            *(uint4*)(Wh + ob) = vh;
            *(uint4*)(Wl + ob) = vl;
        }
    } else {
        const int idx = (bid - 768) * 256 + tid;   // < N_PTS*32
        const int n = idx >> 5, l = idx & 31;
        const float xv = x[n];
        float v;
        if (l < 16) v = sinf(xv * freq[l]);
        else        v = cosf(xv * freq[l - 16]);
        h0[idx] = v;
    }
}

// ---------------------------------------------------------------------------
// One GEMM layer phase: out(128 rows,256) = Aug(h)(128,9F) @ W(9F,256),
// split-bf16 32x32x16 MFMA, split-K parity, chain-broken groups (R10 code).
// Wave (rg, ks): 32 rows, chunks c with c%2==ks. Caller must __syncthreads()
// before the next phase touches WB.
// A-frag layout (32x32x16): row = lane&31, k = (lane>>5)*8 + j.
// B-frag layout:            col = lane&31, k = (lane>>5)*8 + j.
// C/D layout:               col = lane&31, row = (reg&3)+8*(reg>>2)+4*(lane>>5).
template <int F>
__device__ __forceinline__ void layer_phase(
    const int tid, const int row0,
    const float* __restrict__ hin,
    const short* __restrict__ Wh, const short* __restrict__ Wl,
    float* __restrict__ out,
    short (&WB)[2][2][2][8192]) {
    constexpr int KBC = F / 4;         // basis chunks (8F/32)
    constexpr int KSC = F / 32;        // silu chunks
    constexpr int NC  = KBC + KSC;
    constexpr int NP  = (NC + 1) / 2;  // chunk pairs (last may be singleton)

    const int wv   = tid >> 6;
    const int rg   = wv & 3;           // row-group 0..3
    const int ks   = wv >> 2;          // chunk parity 0..1
    const int lane = tid & 63;
    const int lc   = lane & 31;        // A row / B col within tile
    const int half = lane >> 5;        // k-subgroup
    const int r    = row0 + rg * 32 + lc;   // this lane's A row
    const float* hrow = hin + (size_t)r * F;

    f32x16 acc[8];
#pragma unroll
    for (int a = 0; a < 8; ++a)
#pragma unroll
        for (int e = 0; e < 16; ++e) acc[a][e] = 0.f;

    auto stage_pair = [&](int p, int buf) {
#pragma unroll
        for (int cip = 0; cip < 2; ++cip) {
            int c = 2 * p + cip;
            if (c < NC) {
                const size_t gof = (size_t)c * 8192;
#pragma unroll
                for (int i = 0; i < 2; ++i) {
                    int e = tid * 8 + i * 4096;
                    gld16(Wh + gof + e, &WB[buf][cip][0][e]);
                    gld16(Wl + gof + e, &WB[buf][cip][1][e]);
                }
            }
        }
    };

    // stage pair 0 into buf 0
    stage_pair(0, 0);

    // preload x for my first chunk (c0 = ks, always a basis chunk):
    // feature = c*4 + kh*2 + half
    float xreg[2];
#pragma unroll
    for (int kh = 0; kh < 2; ++kh)
        xreg[kh] = hrow[ks * 4 + kh * 2 + half];
    __syncthreads();

    for (int p = 0; p < NP; ++p) {
        const int cur = p & 1;
        if (p + 1 < NP) stage_pair(p + 1, cur ^ 1);

        const int c = 2 * p + ks;      // my chunk this pair
        if (c < NC) {
            // ---- A fragments (registers), one per k-half ----
            Frag ah[2], al[2];
            if (c < KBC) {
                float x0 = xreg[0], x1 = xreg[1];
                if (c + 2 < KBC) {   // prefetch activations for my next chunk
#pragma unroll
                    for (int kh = 0; kh < 2; ++kh)
                        xreg[kh] = hrow[(c + 2) * 4 + kh * 2 + half];
                }
                build_basis_frag(x0, ah[0], al[0]);
                build_basis_frag(x1, ah[1], al[1]);
            } else {
                const int fb = (c - KBC) * 32 + half * 8;
#pragma unroll
                for (int kh = 0; kh < 2; ++kh)
                    build_silu_frag(&hrow[fb + kh * 16], ah[kh], al[kh]);
            }

            // ---- MFMA: product-major ct-groups of 4 (chain-broken) ----
            const short* WHp = WB[cur][ks][0];
            const short* WLp = WB[cur][ks][1];
#pragma unroll
            for (int kh = 0; kh < 2; ++kh) {
#pragma unroll
                for (int g = 0; g < 2; ++g) {
                    const int cb  = g * 4;
                    const int ob  = ((kh * 2 + half) * 256 + cb * 32 + lc) * 8;
                    Frag w0, w1, w2, w3;
                    w0.v = *(const short8*)&WHp[ob];
                    w1.v = *(const short8*)&WHp[ob + 256];
                    w2.v = *(const short8*)&WHp[ob + 512];
                    w3.v = *(const short8*)&WHp[ob + 768];
                    acc[cb + 0] = __builtin_amdgcn_mfma_f32_32x32x16_bf16(ah[kh].v, w0.v, acc[cb + 0], 0, 0, 0);
                    acc[cb + 1] = __builtin_amdgcn_mfma_f32_32x32x16_bf16(ah[kh].v, w1.v, acc[cb + 1], 0, 0, 0);
                    acc[cb + 2] = __builtin_amdgcn_mfma_f32_32x32x16_bf16(ah[kh].v, w2.v, acc[cb + 2], 0, 0, 0);
                    acc[cb + 3] = __builtin_amdgcn_mfma_f32_32x32x16_bf16(ah[kh].v, w3.v, acc[cb + 3], 0, 0, 0);
                    acc[cb + 0] = __builtin_amdgcn_mfma_f32_32x32x16_bf16(al[kh].v, w0.v, acc[cb + 0], 0, 0, 0);
                    acc[cb + 1] = __builtin_amdgcn_mfma_f32_32x32x16_bf16(al[kh].v, w1.v, acc[cb + 1], 0, 0, 0);
                    acc[cb + 2] = __builtin_amdgcn_mfma_f32_32x32x16_bf16(al[kh].v, w2.v, acc[cb + 2], 0, 0, 0);
                    acc[cb + 3] = __builtin_amdgcn_mfma_f32_32x32x16_bf16(al[kh].v, w3.v, acc[cb + 3], 0, 0, 0);
                    Frag v0, v1, v2, v3;
                    v0.v = *(const short8*)&WLp[ob];
                    v1.v = *(const short8*)&WLp[ob + 256];
                    v2.v = *(const short8*)&WLp[ob + 512];
                    v3.v = *(const short8*)&WLp[ob + 768];
                    acc[cb + 0] = __builtin_amdgcn_mfma_f32_32x32x16_bf16(ah[kh].v, v0.v, acc[cb + 0], 0, 0, 0);
                    acc[cb + 1] = __builtin_amdgcn_mfma_f32_32x32x16_bf16(ah[kh].v, v1.v, acc[cb + 1], 0, 0, 0);
                    acc[cb + 2] = __builtin_amdgcn_mfma_f32_32x32x16_bf16(ah[kh].v, v2.v, acc[cb + 2], 0, 0, 0);
                    acc[cb + 3] = __builtin_amdgcn_mfma_f32_32x32x16_bf16(ah[kh].v, v3.v, acc[cb + 3], 0, 0, 0);
                }
            }
        }
        __syncthreads();
    }

    // ---- cross-ks reduction via LDS (WB reused as 32K-float scratch) ----
    // Tile (rg, ks, cti) = 1024 floats at ((rg*2+ks)*4+cti)*1024; within:
    // e4*256 + lane*4 (contiguous 16B/lane — conflict-free b128 pattern).
    // Wave (rg, ks) writes its partials for the OTHER half's col-tiles, then
    // reads partner's partials for its OWN half, adds, stores to global.
    float* red = (float*)WB;
    {
        float* wp = red + (size_t)((rg * 2 + ks) * 4) * 1024 + lane * 4;
        if (ks == 0) {
#pragma unroll
            for (int cti = 0; cti < 4; ++cti)
#pragma unroll
                for (int e4 = 0; e4 < 4; ++e4) {
                    f32x4 v = {acc[4 + cti][e4 * 4 + 0], acc[4 + cti][e4 * 4 + 1],
                               acc[4 + cti][e4 * 4 + 2], acc[4 + cti][e4 * 4 + 3]};
                    *(f32x4*)(wp + cti * 1024 + e4 * 256) = v;
                }
        } else {
#pragma unroll
            for (int cti = 0; cti < 4; ++cti)
#pragma unroll
                for (int e4 = 0; e4 < 4; ++e4) {
                    f32x4 v = {acc[cti][e4 * 4 + 0], acc[cti][e4 * 4 + 1],
                               acc[cti][e4 * 4 + 2], acc[cti][e4 * 4 + 3]};
                    *(f32x4*)(wp + cti * 1024 + e4 * 256) = v;
                }
        }
    }
    __syncthreads();
    {
        const float* rp = red + (size_t)((rg * 2 + (1 - ks)) * 4) * 1024 + lane * 4;
        if (ks == 0) {
#pragma unroll
            for (int cti = 0; cti < 4; ++cti) {
                const int colg = cti * 32 + lc;
#pragma unroll
                for (int e4 = 0; e4 < 4; ++e4) {
                    f32x4 v = *(const f32x4*)(rp + cti * 1024 + e4 * 256);
#pragma unroll
                    for (int j = 0; j < 4; ++j) {
                        const int rgi  = e4 * 4 + j;
                        const int rowg = row0 + rg * 32 + (rgi & 3) + 8 * (rgi >> 2) + 4 * half;
                        out[(size_t)rowg * 256 + colg] = acc[cti][rgi] + v[j];
                    }
                }
            }
        } else {
#pragma unroll
            for (int cti = 0; cti < 4; ++cti) {
                const int colg = (4 + cti) * 32 + lc;
#pragma unroll
                for (int e4 = 0; e4 < 4; ++e4) {
                    f32x4 v = *(const f32x4*)(rp + cti * 1024 + e4 * 256);
#pragma unroll
                    for (int j = 0; j < 4; ++j) {
                        const int rgi  = e4 * 4 + j;
                        const int rowg = row0 + rg * 32 + (rgi & 3) + 8 * (rgi >> 2) + 4 * half;
                        out[(size_t)rowg * 256 + colg] = acc[4 + cti][rgi] + v[j];
                    }
                }
            }
        }
    }
}

// ---------------------------------------------------------------------------
// Fused network: 3 GEMM phases + final-layer phase, per-block row ownership.
__global__ __launch_bounds__(512, 2)
void fused_net(const float* __restrict__ h0,
               const short* __restrict__ Wh0, const short* __restrict__ Wl0,
               float* __restrict__ hA,
               const short* __restrict__ Wh1, const short* __restrict__ Wl1,
               float* __restrict__ hB,
               const short* __restrict__ Wh2, const short* __restrict__ Wl2,
               const float* __restrict__ sw3, const float* __restrict__ ss3,
               const float* __restrict__ bw3,
               float* __restrict__ outp) {
    __shared__ short WB[2][2][2][8192];   // 128 KB, reused by every phase
    const int tid  = threadIdx.x;
    const int row0 = blockIdx.x * 128;

    layer_phase<32>(tid, row0, h0, Wh0, Wl0, hA, WB);
    __syncthreads();   // epilogue red-reads retired; hA writes drained
    layer_phase<256>(tid, row0, hA, Wh1, Wl1, hB, WB);
    __syncthreads();
    layer_phase<256>(tid, row0, hB, Wh2, Wl2, hA, WB);
    __syncthreads();

    // ---- final layer (n_out=1): quad-per-row, closed-form cubic basis ----
    const int lr  = tid >> 2;          // local row 0..127
    const int qq  = tid & 3;           // quad lane -> feature block
    const int row = row0 + lr;
    const float* hrow = hA + (size_t)row * 256;
    const int fb = qq * 64;
    float acc = 0.f;
#pragma unroll 4
    for (int it = 0; it < 16; ++it) {
        float4 xv = *(const float4*)(hrow + fb + it * 4);
        float xs[4] = {xv.x, xv.y, xv.z, xv.w};
#pragma unroll
        for (int j = 0; j < 4; ++j) {
            const int f = fb + it * 4 + j;
            const float x = xs[j];
            float t  = (x + 2.2f) * 2.5f;
            float fl = floorf(t);
            int   i  = (int)fl;
            float w  = t - fl;
            float w2 = w * w, w3 = w2 * w;
            const float s = 1.0f / 6.0f;
            float q0 = w3 * s;
            float q1 = (-3.f * w3 + 3.f * w2 + 3.f * w + 1.f) * s;
            float q2 = (3.f * w3 - 6.f * w2 + 4.f) * s;
            float omw = 1.f - w;
            float q3 = omw * omw * omw * s;
            const float* swf = sw3 + f * 8;
            int j0 = i, j1 = i - 1, j2 = i - 2, j3 = i - 3;
            float v0 = swf[j0 < 0 ? 0 : (j0 > 7 ? 7 : j0)];
            float v1 = swf[j1 < 0 ? 0 : (j1 > 7 ? 7 : j1)];
            float v2 = swf[j2 < 0 ? 0 : (j2 > 7 ? 7 : j2)];
            float v3 = swf[j3 < 0 ? 0 : (j3 > 7 ? 7 : j3)];
            float dot = 0.0f;
            dot += (j0 >= 0 && j0 < 8) ? q0 * v0 : 0.f;
            dot += (j1 >= 0 && j1 < 8) ? q1 * v1 : 0.f;
            dot += (j2 >= 0 && j2 < 8) ? q2 * v2 : 0.f;
            dot += (j3 >= 0 && j3 < 8) ? q3 * v3 : 0.f;
            acc = fmaf(dot, ss3[f], acc);
            acc = fmaf(x / (1.0f + __expf(-x)), bw3[f], acc);
        }
    }
    acc += __shfl_xor(acc, 1);
    acc += __shfl_xor(acc, 2);
    if (qq == 0) outp[row] = acc;
}

// ---------------------------------------------------------------------------
// ws layout (bytes)
#define WH0_OFF 0u
#define WL0_OFF (WH0_OFF + 147456u)      // 288*256*2
#define WH1_OFF (WL0_OFF + 147456u)
#define WL1_OFF (WH1_OFF + 1179648u)     // 2304*256*2
#define WH2_OFF (WL1_OFF + 1179648u)
#define WL2_OFF (WH2_OFF + 1179648u)
#define H0_OFF  (WL2_OFF + 1179648u)     // 32768*32*4
#define HA_OFF  (H0_OFF + 4194304u)      // 32768*256*4
#define HB_OFF  (HA_OFF + 33554432u)
// total = 76,316,672 B

extern "C" void kernel_launch(void* const* d_in, const int* in_sizes, int n_in,
                              void* d_out, int out_size, void* d_ws, size_t ws_size,
                              hipStream_t stream) {
    const float* x    = (const float*)d_in[0];
    const float* freq = (const float*)d_in[1];
    const float* bw0  = (const float*)d_in[2];
    const float* sw0  = (const float*)d_in[3];
    const float* ss0  = (const float*)d_in[4];
    const float* bw1  = (const float*)d_in[5];
    const float* sw1  = (const float*)d_in[6];
    const float* ss1  = (const float*)d_in[7];
    const float* bw2  = (const float*)d_in[8];
    const float* sw2  = (const float*)d_in[9];
    const float* ss2  = (const float*)d_in[10];
    const float* bw3  = (const float*)d_in[11];
    const float* sw3  = (const float*)d_in[12];
    const float* ss3  = (const float*)d_in[13];

    char* ws = (char*)d_ws;
    short* Wh0 = (short*)(ws + WH0_OFF);
    short* Wl0 = (short*)(ws + WL0_OFF);
    short* Wh1 = (short*)(ws + WH1_OFF);
    short* Wl1 = (short*)(ws + WL1_OFF);
    short* Wh2 = (short*)(ws + WH2_OFF);
    short* Wl2 = (short*)(ws + WL2_OFF);
    float* h0 = (float*)(ws + H0_OFF);
    float* hA = (float*)(ws + HA_OFF);
    float* hB = (float*)(ws + HB_OFF);
    float* outp = (float*)d_out;

    // fused: 3 preps (blocks 0..767) + encode (blocks 768..4863)
    setup_kernel<<<768 + (N_PTS * 32) / 256, 256, 0, stream>>>(
        x, freq, bw0, sw0, ss0, bw1, sw1, ss1, bw2, sw2, ss2,
        Wh0, Wl0, Wh1, Wl1, Wh2, Wl2, h0);

    // whole network in one launch (rows are block-local through all layers)
    fused_net<<<N_PTS / 128, 512, 0, stream>>>(
        h0, Wh0, Wl0, hA, Wh1, Wl1, hB, Wh2, Wl2, sw3, ss3, bw3, outp);
}